// Round 1
// 419.704 us; speedup vs baseline: 1.0841x; 1.0841x over previous
//
#include <hip/hip_runtime.h>

// PureWaveAttention B=2,T=2048,D=1024,H=16,NW=64,HD=64 — fp32 I/O, all GEMMs
// on MFMA via 2-term fp16 split: a = hi + lo/2048 (lo stored pre-scaled x2048).
// C = hh(hi,hi) + mx(hi,lo + lo,hi)/2048. Rel err 2^-22 -> fp32-equivalent.
// Pipeline:
//  0) xsplit: x fp32 -> xhi/xlo fp16 (aliases G region, dead until chunk_kv)
//  0b) wsplit: W{qf,qp,kf,kp,v,o} fp32[k][n] -> Whi/Wlo fp16[n][k]
//  1) proj: qn/kn = normalize(sin((x@Wf+bf)*t + (x@Wp+bp))) -> fp16
//     NEW: 128-row tile, mfma_32x32x16, XOR-swizzled 128B-row LDS (bank-
//     conflict-free b128), reg-prefetch of next k-tile. Was LDS-bound w/
//     3.1e7 bank conflicts at 163us.
//  2) vgemm: v = x@Wv+bv -> fp32 in d_out (consumed before out-gemm), A from
//     pre-split xhi/xlo (AF32 split removed from hot loop)
//  3) chunk_kv -> G; prefix -> M (NEW: 512 blocks, was 32 = latency-bound);
//     attn_chunk -> att split fp16 (aliases qnh/knh)
//  4) outgemm: d_out = att@Wo+bo
// ws (56 MB): Wsplit 24 | qnh 8 | knh 8 | G 16 (xhi/xlo alias G before chunk_kv)

#define Bb 2
#define Tt 2048
#define Dd 1024
#define Hh 16
#define NC 32

typedef _Float16 half_t;
typedef _Float16 half8 __attribute__((ext_vector_type(8)));
typedef _Float16 half4h __attribute__((ext_vector_type(4)));
typedef float float4v __attribute__((ext_vector_type(4)));
typedef float f32x16 __attribute__((ext_vector_type(16)));

#define MFMA16(a, b, c) __builtin_amdgcn_mfma_f32_16x16x32_f16((a), (b), (c), 0, 0, 0)
#define MFMA32(a, b, c) __builtin_amdgcn_mfma_f32_32x32x16_f16((a), (b), (c), 0, 0, 0)

// ---------------------------------------------------------------------------
// Kernel -1: split x fp32 -> xhi, xlo fp16 (lo pre-scaled x2048).
// ---------------------------------------------------------------------------
__global__ __launch_bounds__(256) void xsplit_kernel(
    const float* __restrict__ X, half_t* __restrict__ XHI, half_t* __restrict__ XLO)
{
  const size_t i = ((size_t)blockIdx.x * 256 + threadIdx.x) * 8;
  float4 a = *(const float4*)&X[i];
  float4 b = *(const float4*)&X[i + 4];
  const float av[8] = {a.x, a.y, a.z, a.w, b.x, b.y, b.z, b.w};
  half8 hv, lv;
  #pragma unroll
  for (int j = 0; j < 8; ++j) {
    half_t hx = (half_t)av[j];
    hv[j] = hx; lv[j] = (half_t)((av[j] - (float)hx) * 2048.f);
  }
  *(half8*)&XHI[i] = hv;
  *(half8*)&XLO[i] = lv;
}

// ---------------------------------------------------------------------------
// Kernel 0: split+transpose weights: W[k][n] fp32 -> hi[n][k], lo[n][k] fp16.
// Per matrix: hi at m*2097152 halves, lo at +1048576.
// ---------------------------------------------------------------------------
__global__ __launch_bounds__(256) void wsplit_kernel(
    const float* __restrict__ W0, const float* __restrict__ W1,
    const float* __restrict__ W2, const float* __restrict__ W3,
    const float* __restrict__ W4, const float* __restrict__ W5,
    half_t* __restrict__ WSP)
{
  __shared__ float Ld[64][68];
  const int tid = threadIdx.x;
  const int m = blockIdx.z;
  const float* W = (m == 0) ? W0 : (m == 1) ? W1 : (m == 2) ? W2
                 : (m == 3) ? W3 : (m == 4) ? W4 : W5;
  const int k0 = blockIdx.x * 64, n0 = blockIdx.y * 64;
  const int r = tid >> 2, c4 = (tid & 3) * 16;
  #pragma unroll
  for (int i = 0; i < 4; ++i)
    *(float4*)&Ld[r][c4 + i * 4] =
        *(const float4*)&W[(size_t)(k0 + r) * Dd + n0 + c4 + i * 4];
  __syncthreads();
  half_t* hi = WSP + (size_t)m * 2097152;
  half_t* lo = hi + 1048576;
  const int n = tid >> 2, kc = (tid & 3) * 16;
  half8 hv0, hv1, lv0, lv1;
  #pragma unroll
  for (int i = 0; i < 8; ++i) {
    float v0 = Ld[kc + i][n];
    half_t h0 = (half_t)v0;
    hv0[i] = h0; lv0[i] = (half_t)((v0 - (float)h0) * 2048.f);
    float v1 = Ld[kc + 8 + i][n];
    half_t h1 = (half_t)v1;
    hv1[i] = h1; lv1[i] = (half_t)((v1 - (float)h1) * 2048.f);
  }
  *(half8*)&hi[(size_t)(n0 + n) * Dd + k0 + kc]     = hv0;
  *(half8*)&hi[(size_t)(n0 + n) * Dd + k0 + kc + 8] = hv1;
  *(half8*)&lo[(size_t)(n0 + n) * Dd + k0 + kc]     = lv0;
  *(half8*)&lo[(size_t)(n0 + n) * Dd + k0 + kc + 8] = lv1;
}

// ---------------------------------------------------------------------------
// Kernel 1: proj. Block = 128 t-rows x (64 F | 64 P) cols for head h, pair p.
// 4 waves; wave w owns rows 32w..32w+31, all 128 cols, as 4 32x32 acc tiles
// (F0,F1,P0,P1) x (hh,mx) via mfma_f32_32x32x16_f16.
// LDS: rows of 128B = 8x16B chunks [hi k0..31 | lo k0..31], chunk XOR-swizzled
// by (row&7) -> every b128 frag read / staged write hits 32 banks x8 (optimal).
// Next k-tile prefetched to regs during MFMA. Epilogue: lane holds cols
// rl,rl+32 of rows (j&3)+8(j>>2)+4kq; 32-lane butterfly for L2 norm.
// ---------------------------------------------------------------------------
__global__ __launch_bounds__(256, 2) void proj_kernel(
    const half_t* __restrict__ XHI, const half_t* __restrict__ XLO,
    const half_t* __restrict__ WSP,
    const float* __restrict__ bqf, const float* __restrict__ bqp,
    const float* __restrict__ bkf, const float* __restrict__ bkp,
    half_t* __restrict__ QNH, half_t* __restrict__ KNH)
{
  __shared__ __align__(16) half_t As[128][64];
  __shared__ __align__(16) half_t Bs[128][64];
  const int tid = threadIdx.x;
  const int mb = blockIdx.x, h = blockIdx.y;
  const int b = blockIdx.z >> 1, p = blockIdx.z & 1;
  const int t0 = mb * 128, row0 = b * Tt + t0, col0 = h * 64;
  const half_t* WF = WSP + (size_t)(2 * p) * 2097152;      // hi; lo at +1048576
  const half_t* WP = WSP + (size_t)(2 * p + 1) * 2097152;
  const float* BF = p ? bkf : bqf;
  const float* BP = p ? bkp : bqp;
  half_t* OUTH = p ? KNH : QNH;

  f32x16 hh[4], mx[4];
  #pragma unroll
  for (int i = 0; i < 4; ++i) { hh[i] = (f32x16)(0.f); mx[i] = (f32x16)(0.f); }

  const int lane = tid & 63, w = tid >> 6;
  const int rl = lane & 31, kq = lane >> 5;
  const int sw = rl & 7;                       // frag-read swizzle

  // staging: thread handles row sr (A and B), k-half kh (16 halfs)
  const int sr = tid >> 1, kh = tid & 1;
  const int swr = sr & 7;
  const half_t* GAh = &XHI[(size_t)(row0 + sr) * Dd + 16 * kh];
  const half_t* GAl = &XLO[(size_t)(row0 + sr) * Dd + 16 * kh];
  const half_t* WB = (sr < 64) ? (WF + (size_t)(col0 + sr) * Dd)
                               : (WP + (size_t)(col0 + sr - 64) * Dd);
  const half_t* GBh = WB + 16 * kh;
  const half_t* GBl = WB + 1048576 + 16 * kh;
  half_t* SA0 = &As[sr][((2 * kh + 0) ^ swr) * 8];
  half_t* SA1 = &As[sr][((2 * kh + 1) ^ swr) * 8];
  half_t* SA2 = &As[sr][((4 + 2 * kh) ^ swr) * 8];
  half_t* SA3 = &As[sr][((5 + 2 * kh) ^ swr) * 8];
  half_t* SB0 = &Bs[sr][((2 * kh + 0) ^ swr) * 8];
  half_t* SB1 = &Bs[sr][((2 * kh + 1) ^ swr) * 8];
  half_t* SB2 = &Bs[sr][((4 + 2 * kh) ^ swr) * 8];
  half_t* SB3 = &Bs[sr][((5 + 2 * kh) ^ swr) * 8];

  half8 ra0 = *(const half8*)&GAh[0], ra1 = *(const half8*)&GAh[8];
  half8 ra2 = *(const half8*)&GAl[0], ra3 = *(const half8*)&GAl[8];
  half8 rb0 = *(const half8*)&GBh[0], rb1 = *(const half8*)&GBh[8];
  half8 rb2 = *(const half8*)&GBl[0], rb3 = *(const half8*)&GBl[8];

  for (int k0 = 0; k0 < Dd; k0 += 32) {
    *(half8*)SA0 = ra0; *(half8*)SA1 = ra1;
    *(half8*)SA2 = ra2; *(half8*)SA3 = ra3;
    *(half8*)SB0 = rb0; *(half8*)SB1 = rb1;
    *(half8*)SB2 = rb2; *(half8*)SB3 = rb3;
    __syncthreads();
    if (k0 + 32 < Dd) {          // prefetch next tile under the MFMAs
      ra0 = *(const half8*)&GAh[k0 + 32]; ra1 = *(const half8*)&GAh[k0 + 40];
      ra2 = *(const half8*)&GAl[k0 + 32]; ra3 = *(const half8*)&GAl[k0 + 40];
      rb0 = *(const half8*)&GBh[k0 + 32]; rb1 = *(const half8*)&GBh[k0 + 40];
      rb2 = *(const half8*)&GBl[k0 + 32]; rb3 = *(const half8*)&GBl[k0 + 40];
    }
    #pragma unroll
    for (int ks = 0; ks < 2; ++ks) {
      half8 ahi = *(const half8*)&As[32 * w + rl][((2 * ks + kq) ^ sw) * 8];
      half8 alo = *(const half8*)&As[32 * w + rl][((4 + 2 * ks + kq) ^ sw) * 8];
      #pragma unroll
      for (int tn = 0; tn < 4; ++tn) {
        half8 bhi = *(const half8*)&Bs[32 * tn + rl][((2 * ks + kq) ^ sw) * 8];
        half8 blo = *(const half8*)&Bs[32 * tn + rl][((4 + 2 * ks + kq) ^ sw) * 8];
        hh[tn] = MFMA32(ahi, bhi, hh[tn]);
        mx[tn] = MFMA32(ahi, blo, mx[tn]);
        mx[tn] = MFMA32(alo, bhi, mx[tn]);
      }
    }
    __syncthreads();
  }

  const float bf0 = BF[col0 + rl], bf1 = BF[col0 + 32 + rl];
  const float bp0 = BP[col0 + rl], bp1 = BP[col0 + 32 + rl];
  #pragma unroll
  for (int j = 0; j < 16; ++j) {
    const int rt = (j & 3) + 8 * (j >> 2) + 4 * kq;   // row within 32-tile
    const float tf = (float)(t0 + 32 * w + rt);
    float f0 = hh[0][j] + mx[0][j] * (1.f / 2048.f) + bf0;
    float f1 = hh[1][j] + mx[1][j] * (1.f / 2048.f) + bf1;
    float p0 = hh[2][j] + mx[2][j] * (1.f / 2048.f) + bp0;
    float p1 = hh[3][j] + mx[3][j] * (1.f / 2048.f) + bp1;
    float w0 = sinf(fmaf(f0, tf, p0));
    float w1 = sinf(fmaf(f1, tf, p1));
    float ss = w0 * w0 + w1 * w1;
    ss += __shfl_xor(ss, 1); ss += __shfl_xor(ss, 2);
    ss += __shfl_xor(ss, 4); ss += __shfl_xor(ss, 8);
    ss += __shfl_xor(ss, 16);
    const float inv = 1.f / fmaxf(sqrtf(ss), 1e-12f);
    half_t* op = &OUTH[((size_t)(b * Tt) + t0 + 32 * w + rt) * Dd + col0];
    op[rl]      = (half_t)(w0 * inv);
    op[32 + rl] = (half_t)(w1 * inv);
  }
}

// ---------------------------------------------------------------------------
// Kernel 2/4: GEMM C[M,1024] = A@W + bias, split-fp16 MFMA. M-tile 64,
// N-tile 128. A from pre-split halves.
// ---------------------------------------------------------------------------
template<bool AF32>
__global__ __launch_bounds__(256, 3) void gemm_split_kernel(
    const float* __restrict__ A32,
    const half_t* __restrict__ AHI, const half_t* __restrict__ ALO,
    const half_t* __restrict__ WHI,   // lo at +1048576
    const float* __restrict__ BIAS, float* __restrict__ OUT)
{
  __shared__ half_t Ahi[64][40], Alo[64][40];
  __shared__ half_t Bhi[128][40], Blo[128][40];
  const int tid = threadIdx.x;
  const int m0 = blockIdx.x * 64, n0 = blockIdx.y * 128;

  float4v hh[8], mx[8];
  #pragma unroll
  for (int i = 0; i < 8; ++i) { hh[i] = (float4v){0.f,0.f,0.f,0.f}; mx[i] = hh[i]; }

  const int lane = tid & 63, wave = tid >> 6;
  const int lm = lane & 15, lq = lane >> 4;
  const int wrow = wave * 16;
  const int sar = tid >> 2, sak = (tid & 3) * 8;

  for (int k0 = 0; k0 < Dd; k0 += 32) {
    if constexpr (AF32) {
      #pragma unroll
      for (int j = 0; j < 2; ++j) {
        const int idx = tid + j * 256;
        const int r = idx >> 3, kc = (idx & 7) * 4;
        float4 a = *(const float4*)&A32[(size_t)(m0 + r) * Dd + k0 + kc];
        const float av[4] = {a.x, a.y, a.z, a.w};
        half4h hv, lv;
        #pragma unroll
        for (int i = 0; i < 4; ++i) {
          half_t hx = (half_t)av[i];
          hv[i] = hx; lv[i] = (half_t)((av[i] - (float)hx) * 2048.f);
        }
        *(half4h*)&Ahi[r][kc] = hv;
        *(half4h*)&Alo[r][kc] = lv;
      }
    } else {
      *(half8*)&Ahi[sar][sak] = *(const half8*)&AHI[(size_t)(m0 + sar) * Dd + k0 + sak];
      *(half8*)&Alo[sar][sak] = *(const half8*)&ALO[(size_t)(m0 + sar) * Dd + k0 + sak];
    }
    #pragma unroll
    for (int j = 0; j < 2; ++j) {
      const int idx = tid + j * 256;
      const int n = idx >> 2, kp = (idx & 3) * 8;
      *(half8*)&Bhi[n][kp] = *(const half8*)&WHI[(size_t)(n0 + n) * Dd + k0 + kp];
      *(half8*)&Blo[n][kp] = *(const half8*)&WHI[1048576 + (size_t)(n0 + n) * Dd + k0 + kp];
    }
    __syncthreads();
    half8 ahi = *(const half8*)&Ahi[wrow + lm][lq * 8];
    half8 alo = *(const half8*)&Alo[wrow + lm][lq * 8];
    #pragma unroll
    for (int tn = 0; tn < 8; ++tn) {
      half8 bhi = *(const half8*)&Bhi[tn * 16 + lm][lq * 8];
      half8 blo = *(const half8*)&Blo[tn * 16 + lm][lq * 8];
      hh[tn] = MFMA16(ahi, bhi, hh[tn]);
      mx[tn] = MFMA16(ahi, blo, mx[tn]);
      mx[tn] = MFMA16(alo, bhi, mx[tn]);
    }
    __syncthreads();
  }

  #pragma unroll
  for (int tn = 0; tn < 8; ++tn) {
    const float bn = BIAS[n0 + tn * 16 + lm];
    #pragma unroll
    for (int r = 0; r < 4; ++r) {
      const int row = m0 + wrow + lq * 4 + r;
      OUT[(size_t)row * Dd + n0 + tn * 16 + lm] =
          hh[tn][r] + mx[tn][r] * (1.f / 2048.f) + bn;
    }
  }
}

// ---------------------------------------------------------------------------
// Kernel 3a: G_c[w][d] = sum_{s in c} K[s][w]*V[s][d]. K from fp16, V fp32.
// ---------------------------------------------------------------------------
__global__ __launch_bounds__(256) void chunk_kv_kernel(
    const half_t* __restrict__ KNH, const float* __restrict__ V,
    float* __restrict__ G)
{
  __shared__ float Ks[64][64];
  __shared__ float Vs[64][64];
  const int tid = threadIdx.x;
  const int c = blockIdx.x, h = blockIdx.y, b = blockIdx.z;
  const int s0 = c * 64;
  const int lr = tid >> 2, lc = (tid & 3) * 16;
  {
    const half_t* krow = &KNH[(size_t)(b * Tt + s0 + lr) * Dd + h * 64 + lc];
    half8 ka = *(const half8*)&krow[0];
    half8 kb = *(const half8*)&krow[8];
    #pragma unroll
    for (int i = 0; i < 8; ++i) {
      Ks[lr][lc + i] = (float)ka[i];
      Ks[lr][lc + 8 + i] = (float)kb[i];
    }
    const float* vrow = &V[(size_t)(b * Tt + s0 + lr) * Dd + h * 64 + lc];
    #pragma unroll
    for (int i = 0; i < 4; ++i)
      *(float4*)&Vs[lr][lc + i * 4] = *(const float4*)&vrow[i * 4];
  }
  __syncthreads();

  const int ty = tid >> 4, tx = tid & 15;
  float g[4][4] = {{0.f}};
  #pragma unroll 4
  for (int s = 0; s < 64; ++s) {
    float4 kv = *(const float4*)&Ks[s][ty * 4];
    float4 vv = *(const float4*)&Vs[s][tx * 4];
    const float* k_ = (const float*)&kv;
    const float* v_ = (const float*)&vv;
    #pragma unroll
    for (int i = 0; i < 4; ++i)
      #pragma unroll
      for (int j = 0; j < 4; ++j)
        g[i][j] = fmaf(k_[i], v_[j], g[i][j]);
  }
  float* Gp = G + (((size_t)(b * Hh + h) * NC + c) << 12);
  #pragma unroll
  for (int i = 0; i < 4; ++i)
    *(float4*)&Gp[(ty * 4 + i) * 64 + tx * 4] =
        make_float4(g[i][0], g[i][1], g[i][2], g[i][3]);
}

// ---------------------------------------------------------------------------
// Kernel 3b: in-place exclusive prefix over NC chunk matrices per (b,h).
// NEW: 512 blocks (was 32 -> 12.5% CU occupancy, latency-bound). Each block
// owns 256 of the 4096 elements; thread = 1 float, fully coalesced.
// ---------------------------------------------------------------------------
__global__ __launch_bounds__(256) void prefix_kernel(float* __restrict__ G)
{
  const int seg = blockIdx.x, h = blockIdx.y, b = blockIdx.z;
  float* base = G + (((size_t)(b * Hh + h) * NC) << 12) + seg * 256 + threadIdx.x;
  float acc = 0.f;
  #pragma unroll 4
  for (int c = 0; c < NC; ++c) {
    float* p = base + ((size_t)c << 12);
    const float g = *p;
    *p = acc;
    acc += g;
  }
}

// ---------------------------------------------------------------------------
// Kernel 3c: O_c = (Q_c M_c + tril(Q_c K_c^T) V_c) * scale/sqrt(t+1).
// Q,K from fp16; out split to fp16 hi/lo (lo x2048), aliasing qnh/knh.
// ---------------------------------------------------------------------------
__global__ __launch_bounds__(256) void attn_chunk_kernel(
    const half_t* __restrict__ QNH, const half_t* __restrict__ KNH,
    const float* __restrict__ V, const float* __restrict__ M,
    const float* __restrict__ SCALE,
    half_t* __restrict__ ATTHI, half_t* __restrict__ ATTLO)
{
  __shared__ float Qt[64][68];
  __shared__ float Kt[64][68];
  __shared__ float SM[64][68];
  __shared__ float Vs[64][64];
  const int tid = threadIdx.x;
  const int c = blockIdx.x, h = blockIdx.y, b = blockIdx.z;
  const int t0 = c * 64;
  const int lr = tid >> 2, lc = (tid & 3) * 16;
  {
    const half_t* qrow = &QNH[(size_t)(b * Tt + t0 + lr) * Dd + h * 64 + lc];
    const half_t* krow = &KNH[(size_t)(b * Tt + t0 + lr) * Dd + h * 64 + lc];
    half8 qa = *(const half8*)&qrow[0];
    half8 qb = *(const half8*)&qrow[8];
    half8 ka = *(const half8*)&krow[0];
    half8 kb = *(const half8*)&krow[8];
    #pragma unroll
    for (int i = 0; i < 8; ++i) {
      Qt[lc + i][lr] = (float)qa[i];     Qt[lc + 8 + i][lr] = (float)qb[i];
      Kt[lc + i][lr] = (float)ka[i];     Kt[lc + 8 + i][lr] = (float)kb[i];
    }
    const float* vrow = &V[(size_t)(b * Tt + t0 + lr) * Dd + h * 64 + lc];
    const float* mrow = &M[(((size_t)(b * Hh + h) * NC + c) << 12) + lr * 64 + lc];
    #pragma unroll
    for (int i = 0; i < 4; ++i) {
      *(float4*)&Vs[lr][lc + i * 4] = *(const float4*)&vrow[i * 4];
      *(float4*)&SM[lr][lc + i * 4] = *(const float4*)&mrow[i * 4];
    }
  }
  __syncthreads();

  const int ty = tid >> 4, tx = tid & 15;
  float o[4][4] = {{0.f}};
  float sc[4][4] = {{0.f}};

  #pragma unroll 4
  for (int w = 0; w < 64; ++w) {
    float4 qv = *(const float4*)&Qt[w][ty * 4];
    float4 mv = *(const float4*)&SM[w][tx * 4];
    float4 kv = *(const float4*)&Kt[w][tx * 4];
    const float* q_ = (const float*)&qv;
    const float* m_ = (const float*)&mv;
    const float* k_ = (const float*)&kv;
    #pragma unroll
    for (int i = 0; i < 4; ++i) {
      float qq = q_[i];
      #pragma unroll
      for (int j = 0; j < 4; ++j) {
        o[i][j]  = fmaf(qq, m_[j], o[i][j]);
        sc[i][j] = fmaf(qq, k_[j], sc[i][j]);
      }
    }
  }
  __syncthreads();

  #pragma unroll
  for (int i = 0; i < 4; ++i) {
    const int lt = ty * 4 + i;
    #pragma unroll
    for (int j = 0; j < 4; ++j) {
      const int ls = tx * 4 + j;
      SM[ls][lt] = (ls <= lt) ? sc[i][j] : 0.f;
    }
  }
  __syncthreads();

  #pragma unroll 4
  for (int s = 0; s < 64; ++s) {
    float4 sv = *(const float4*)&SM[s][ty * 4];
    float4 vv = *(const float4*)&Vs[s][tx * 4];
    const float* s_ = (const float*)&sv;
    const float* v_ = (const float*)&vv;
    #pragma unroll
    for (int i = 0; i < 4; ++i)
      #pragma unroll
      for (int j = 0; j < 4; ++j)
        o[i][j] = fmaf(s_[i], v_[j], o[i][j]);
  }

  const float sch = SCALE[h];
  #pragma unroll
  for (int i = 0; i < 4; ++i) {
    const int t = t0 + ty * 4 + i;
    const float fac = sch / sqrtf((float)(t + 1));
    half4h hv, lv;
    #pragma unroll
    for (int j = 0; j < 4; ++j) {
      float v = o[i][j] * fac;
      half_t hx = (half_t)v;
      hv[j] = hx; lv[j] = (half_t)((v - (float)hx) * 2048.f);
    }
    *(half4h*)&ATTHI[(size_t)(b * Tt + t) * Dd + h * 64 + tx * 4] = hv;
    *(half4h*)&ATTLO[(size_t)(b * Tt + t) * Dd + h * 64 + tx * 4] = lv;
  }
}

// ---------------------------------------------------------------------------
extern "C" void kernel_launch(void* const* d_in, const int* in_sizes, int n_in,
                              void* d_out, int out_size, void* d_ws, size_t ws_size,
                              hipStream_t stream) {
  const float* x   = (const float*)d_in[0];
  const float* Wqf = (const float*)d_in[1];
  const float* bqf = (const float*)d_in[2];
  const float* Wkf = (const float*)d_in[3];
  const float* bkf = (const float*)d_in[4];
  const float* Wqp = (const float*)d_in[5];
  const float* bqp = (const float*)d_in[6];
  const float* Wkp = (const float*)d_in[7];
  const float* bkp = (const float*)d_in[8];
  const float* Wv  = (const float*)d_in[9];
  const float* bv  = (const float*)d_in[10];
  const float* Wo  = (const float*)d_in[11];
  const float* bo  = (const float*)d_in[12];
  const float* scale = (const float*)d_in[13];

  // ws layout (56 MB): Wsplit 24 MB | qnh 8 MB | knh 8 MB | G 16 MB
  half_t* WSP = (half_t*)d_ws;                 // 6 mats x (hi 1M + lo 1M) halves
  half_t* qnh = WSP + 12582912;                // 4,194,304 halves
  half_t* knh = qnh + 4194304;
  float*  G   = (float*)(knh + 4194304);
  half_t* xhi = (half_t*)G;                    // x halves alias G: dead before
  half_t* xlo = xhi + 4194304;                 // chunk_kv writes G
  float*  vbuf = (float*)d_out;                // v lives in d_out, consumed
                                               // before the final out-gemm

  xsplit_kernel<<<dim3(2048), 256, 0, stream>>>(x, xhi, xlo);

  // mat order in WSP: 0=qf 1=qp 2=kf 3=kp 4=v 5=o
  wsplit_kernel<<<dim3(16, 16, 6), 256, 0, stream>>>(Wqf, Wqp, Wkf, Wkp, Wv, Wo, WSP);

  proj_kernel<<<dim3(Tt / 128, Hh, Bb * 2), 256, 0, stream>>>(
      xhi, xlo, WSP, bqf, bqp, bkf, bkp, qnh, knh);

  gemm_split_kernel<false><<<dim3((Bb * Tt) / 64, Dd / 128), 256, 0, stream>>>(
      nullptr, xhi, xlo, WSP + (size_t)4 * 2097152, bv, vbuf);

  chunk_kv_kernel<<<dim3(NC, Hh, Bb), 256, 0, stream>>>(knh, vbuf, G);
  prefix_kernel<<<dim3(16, Hh, Bb), 256, 0, stream>>>(G);
  attn_chunk_kernel<<<dim3(NC, Hh, Bb), 256, 0, stream>>>(
      qnh, knh, vbuf, G, scale, qnh /*atthi*/, knh /*attlo*/);

  gemm_split_kernel<false><<<dim3((Bb * Tt) / 64, Dd / 128), 256, 0, stream>>>(
      nullptr, qnh, knh, WSP + (size_t)5 * 2097152, bo, (float*)d_out);
}

// Round 2
// 367.254 us; speedup vs baseline: 1.2389x; 1.1428x over previous
//
#include <hip/hip_runtime.h>

// PureWaveAttention B=2,T=2048,D=1024,H=16,NW=64,HD=64 — fp32 I/O, all GEMMs
// on MFMA via 2-term fp16 split: a = hi + lo/2048 (lo stored pre-scaled x2048).
// C = hh(hi,hi) + mx(hi,lo + lo,hi)/2048. Rel err 2^-22 -> fp32-equivalent.
// Pipeline:
//  0) xsplit: x fp32 -> xhi/xlo fp16 (aliases G region, dead until chunk_kv)
//  0b) wsplit: W{qf,qp,kf,kp,v,o} fp32[k][n] -> Whi/Wlo fp16[n][k]
//  1) proj: qn/kn = normalize(sin((x@Wf+bf)*t + (x@Wp+bp))) -> fp16
//  2) vgemm: v = x@Wv+bv -> fp32 in d_out (consumed before out-gemm)
//  3) chunk_kv -> G; prefix -> M; attn_chunk -> att split fp16 (aliases qnh/knh)
//  4) outgemm: d_out = att@Wo+bo
// R2 changes (proj was 143us, MfmaUtil 32%, 1.9e7 bank conflicts):
//  - staging remap: thread t stages ONE 128B LDS row (r=t&127; A if t<128 else
//    B). Old map (sr=tid>>1) gave only 4 distinct r&7 per 8-lane LDS service
//    group -> 2-way write conflict on every ds_write_b128. New map spans all 8
//    bank groups per octet -> conflict-free writes (reads already clean).
//  - single-barrier dbuf pipeline (T3 minimum-2-phase): LDS [2] buffers, per
//    k-tile { ds_read+MFMA buf[cur] | ds_write tile+1 -> buf[cur^1] | issue
//    global loads tile+2 }, ONE barrier/k-tile (was 2). 2x-unrolled so cur is
//    compile-time.
//  - vgemm/outgemm rewritten on the same 32x32-MFMA core (old 16x16 2-barrier
//    structure shared proj's conflicts).
// ws (56 MB): Wsplit 24 | qnh 8 | knh 8 | G 16 (xhi/xlo alias G before chunk_kv)

#define Bb 2
#define Tt 2048
#define Dd 1024
#define Hh 16
#define NC 32

typedef _Float16 half_t;
typedef _Float16 half8 __attribute__((ext_vector_type(8)));
typedef _Float16 half4h __attribute__((ext_vector_type(4)));
typedef float float4v __attribute__((ext_vector_type(4)));
typedef float f32x16 __attribute__((ext_vector_type(16)));

#define MFMA16(a, b, c) __builtin_amdgcn_mfma_f32_16x16x32_f16((a), (b), (c), 0, 0, 0)
#define MFMA32(a, b, c) __builtin_amdgcn_mfma_f32_32x32x16_f16((a), (b), (c), 0, 0, 0)

// Shared staging macros for the 128x128 dbuf GEMM core. Expect locals:
//   srcHi, srcLo (global row ptrs), dstRow (LDS row ptr in buf0),
//   pc0..pc7 (swizzled chunk byte offsets in halves), rg0..rg7 (half8).
#define LOADREGS(K)                                                       \
  rg0 = *(const half8*)&srcHi[(K)];      rg1 = *(const half8*)&srcHi[(K) + 8];  \
  rg2 = *(const half8*)&srcHi[(K) + 16]; rg3 = *(const half8*)&srcHi[(K) + 24]; \
  rg4 = *(const half8*)&srcLo[(K)];      rg5 = *(const half8*)&srcLo[(K) + 8];  \
  rg6 = *(const half8*)&srcLo[(K) + 16]; rg7 = *(const half8*)&srcLo[(K) + 24];

#define WRITEREGS(BI) {                                                   \
  half_t* d_ = dstRow + (BI) * 8192;                                      \
  *(half8*)&d_[pc0] = rg0; *(half8*)&d_[pc1] = rg1;                       \
  *(half8*)&d_[pc2] = rg2; *(half8*)&d_[pc3] = rg3;                       \
  *(half8*)&d_[pc4] = rg4; *(half8*)&d_[pc5] = rg5;                       \
  *(half8*)&d_[pc6] = rg6; *(half8*)&d_[pc7] = rg7; }

// one k-tile of frag reads + MFMAs from buffer BI (compile-time)
#define KTILE_MFMA(BI)                                                    \
  _Pragma("unroll")                                                       \
  for (int ks = 0; ks < 2; ++ks) {                                        \
    half8 ahi = *(const half8*)&As[BI][32 * w + rl][((2 * ks + kq) ^ sw) * 8];       \
    half8 alo = *(const half8*)&As[BI][32 * w + rl][((4 + 2 * ks + kq) ^ sw) * 8];   \
    _Pragma("unroll")                                                     \
    for (int tn = 0; tn < 4; ++tn) {                                      \
      half8 bhi = *(const half8*)&Bs[BI][32 * tn + rl][((2 * ks + kq) ^ sw) * 8];    \
      half8 blo = *(const half8*)&Bs[BI][32 * tn + rl][((4 + 2 * ks + kq) ^ sw) * 8];\
      hh[tn] = MFMA32(ahi, bhi, hh[tn]);                                  \
      mx[tn] = MFMA32(ahi, blo, mx[tn]);                                  \
      mx[tn] = MFMA32(alo, bhi, mx[tn]);                                  \
    }                                                                     \
  }

// ---------------------------------------------------------------------------
// Kernel -1: split x fp32 -> xhi, xlo fp16 (lo pre-scaled x2048).
// ---------------------------------------------------------------------------
__global__ __launch_bounds__(256) void xsplit_kernel(
    const float* __restrict__ X, half_t* __restrict__ XHI, half_t* __restrict__ XLO)
{
  const size_t i = ((size_t)blockIdx.x * 256 + threadIdx.x) * 8;
  float4 a = *(const float4*)&X[i];
  float4 b = *(const float4*)&X[i + 4];
  const float av[8] = {a.x, a.y, a.z, a.w, b.x, b.y, b.z, b.w};
  half8 hv, lv;
  #pragma unroll
  for (int j = 0; j < 8; ++j) {
    half_t hx = (half_t)av[j];
    hv[j] = hx; lv[j] = (half_t)((av[j] - (float)hx) * 2048.f);
  }
  *(half8*)&XHI[i] = hv;
  *(half8*)&XLO[i] = lv;
}

// ---------------------------------------------------------------------------
// Kernel 0: split+transpose weights: W[k][n] fp32 -> hi[n][k], lo[n][k] fp16.
// Per matrix: hi at m*2097152 halves, lo at +1048576.
// ---------------------------------------------------------------------------
__global__ __launch_bounds__(256) void wsplit_kernel(
    const float* __restrict__ W0, const float* __restrict__ W1,
    const float* __restrict__ W2, const float* __restrict__ W3,
    const float* __restrict__ W4, const float* __restrict__ W5,
    half_t* __restrict__ WSP)
{
  __shared__ float Ld[64][68];
  const int tid = threadIdx.x;
  const int m = blockIdx.z;
  const float* W = (m == 0) ? W0 : (m == 1) ? W1 : (m == 2) ? W2
                 : (m == 3) ? W3 : (m == 4) ? W4 : W5;
  const int k0 = blockIdx.x * 64, n0 = blockIdx.y * 64;
  const int r = tid >> 2, c4 = (tid & 3) * 16;
  #pragma unroll
  for (int i = 0; i < 4; ++i)
    *(float4*)&Ld[r][c4 + i * 4] =
        *(const float4*)&W[(size_t)(k0 + r) * Dd + n0 + c4 + i * 4];
  __syncthreads();
  half_t* hi = WSP + (size_t)m * 2097152;
  half_t* lo = hi + 1048576;
  const int n = tid >> 2, kc = (tid & 3) * 16;
  half8 hv0, hv1, lv0, lv1;
  #pragma unroll
  for (int i = 0; i < 8; ++i) {
    float v0 = Ld[kc + i][n];
    half_t h0 = (half_t)v0;
    hv0[i] = h0; lv0[i] = (half_t)((v0 - (float)h0) * 2048.f);
    float v1 = Ld[kc + 8 + i][n];
    half_t h1 = (half_t)v1;
    hv1[i] = h1; lv1[i] = (half_t)((v1 - (float)h1) * 2048.f);
  }
  *(half8*)&hi[(size_t)(n0 + n) * Dd + k0 + kc]     = hv0;
  *(half8*)&hi[(size_t)(n0 + n) * Dd + k0 + kc + 8] = hv1;
  *(half8*)&lo[(size_t)(n0 + n) * Dd + k0 + kc]     = lv0;
  *(half8*)&lo[(size_t)(n0 + n) * Dd + k0 + kc + 8] = lv1;
}

// ---------------------------------------------------------------------------
// Kernel 1: proj. Block = 128 t-rows x (64 F | 64 P) cols for head h, pair p.
// 4 waves; wave w owns rows 32w..32w+31, all 128 cols, as 4 32x32 acc tiles
// (F0,F1,P0,P1) x (hh,mx) via mfma_f32_32x32x16_f16.
// LDS rows = 128B = 8x16B chunks [hi k0..31 | lo k0..31], chunk c stored at
// c^(row&7). Thread t stages row t&127 (A if t<128 else B) -> octet-clean
// writes AND reads. Single barrier per k-tile, dbuf, 2-tile load lookahead.
// ---------------------------------------------------------------------------
__global__ __launch_bounds__(256, 2) void proj_kernel(
    const half_t* __restrict__ XHI, const half_t* __restrict__ XLO,
    const half_t* __restrict__ WSP,
    const float* __restrict__ bqf, const float* __restrict__ bqp,
    const float* __restrict__ bkf, const float* __restrict__ bkp,
    half_t* __restrict__ QNH, half_t* __restrict__ KNH)
{
  __shared__ __align__(16) half_t As[2][128][64];
  __shared__ __align__(16) half_t Bs[2][128][64];
  const int tid = threadIdx.x;
  const int mb = blockIdx.x, h = blockIdx.y;
  const int b = blockIdx.z >> 1, p = blockIdx.z & 1;
  const int t0 = mb * 128, row0 = b * Tt + t0, col0 = h * 64;
  const half_t* WF = WSP + (size_t)(2 * p) * 2097152;      // hi; lo at +1048576
  const half_t* WP = WSP + (size_t)(2 * p + 1) * 2097152;
  const float* BF = p ? bkf : bqf;
  const float* BP = p ? bkp : bqp;
  half_t* OUTH = p ? KNH : QNH;

  f32x16 hh[4], mx[4];
  #pragma unroll
  for (int i = 0; i < 4; ++i) { hh[i] = (f32x16)(0.f); mx[i] = (f32x16)(0.f); }

  const int lane = tid & 63, w = tid >> 6;
  const int rl = lane & 31, kq = lane >> 5;
  const int sw = rl & 7;                       // frag-read swizzle

  // staging: thread stages one full LDS row r (A rows if tid<128, B if >=128)
  const int r = tid & 127, isB = tid >> 7;
  const int swr = r & 7;
  const half_t* srcHi;
  const half_t* srcLo;
  if (!isB) {
    srcHi = &XHI[(size_t)(row0 + r) * Dd];
    srcLo = &XLO[(size_t)(row0 + r) * Dd];
  } else {
    const half_t* Wb = (r < 64) ? (WF + (size_t)(col0 + r) * Dd)
                                : (WP + (size_t)(col0 + r - 64) * Dd);
    srcHi = Wb; srcLo = Wb + 1048576;
  }
  half_t* dstRow = isB ? &Bs[0][r][0] : &As[0][r][0];
  const int pc0 = ((0 ^ swr)) * 8, pc1 = ((1 ^ swr)) * 8;
  const int pc2 = ((2 ^ swr)) * 8, pc3 = ((3 ^ swr)) * 8;
  const int pc4 = ((4 ^ swr)) * 8, pc5 = ((5 ^ swr)) * 8;
  const int pc6 = ((6 ^ swr)) * 8, pc7 = ((7 ^ swr)) * 8;

  half8 rg0, rg1, rg2, rg3, rg4, rg5, rg6, rg7;
  LOADREGS(0)
  WRITEREGS(0)
  LOADREGS(32)
  __syncthreads();

  #pragma unroll 1
  for (int k0 = 0; k0 < Dd; k0 += 64) {
    // tile k0 in buf0
    KTILE_MFMA(0)
    WRITEREGS(1)                             // tile k0+32 (regs from last load)
    if (k0 + 64 < Dd) { LOADREGS(k0 + 64) }  // tile k0+64
    __syncthreads();
    // tile k0+32 in buf1
    KTILE_MFMA(1)
    if (k0 + 64 < Dd) { WRITEREGS(0) }       // tile k0+64
    if (k0 + 96 < Dd) { LOADREGS(k0 + 96) }  // tile k0+96
    __syncthreads();
  }

  const float bf0 = BF[col0 + rl], bf1 = BF[col0 + 32 + rl];
  const float bp0 = BP[col0 + rl], bp1 = BP[col0 + 32 + rl];
  #pragma unroll
  for (int j = 0; j < 16; ++j) {
    const int rt = (j & 3) + 8 * (j >> 2) + 4 * kq;   // row within 32-tile
    const float tf = (float)(t0 + 32 * w + rt);
    float f0 = hh[0][j] + mx[0][j] * (1.f / 2048.f) + bf0;
    float f1 = hh[1][j] + mx[1][j] * (1.f / 2048.f) + bf1;
    float p0 = hh[2][j] + mx[2][j] * (1.f / 2048.f) + bp0;
    float p1 = hh[3][j] + mx[3][j] * (1.f / 2048.f) + bp1;
    float w0 = sinf(fmaf(f0, tf, p0));
    float w1 = sinf(fmaf(f1, tf, p1));
    float ss = w0 * w0 + w1 * w1;
    ss += __shfl_xor(ss, 1); ss += __shfl_xor(ss, 2);
    ss += __shfl_xor(ss, 4); ss += __shfl_xor(ss, 8);
    ss += __shfl_xor(ss, 16);
    const float inv = 1.f / fmaxf(sqrtf(ss), 1e-12f);
    half_t* op = &OUTH[((size_t)(b * Tt) + t0 + 32 * w + rt) * Dd + col0];
    op[rl]      = (half_t)(w0 * inv);
    op[32 + rl] = (half_t)(w1 * inv);
  }
}

// ---------------------------------------------------------------------------
// Kernel 2/4: GEMM OUT[4096,1024] = A@W + bias. Same dbuf 128x128 core as
// proj: A rows from pre-split AHI/ALO, B rows from WHI (lo at +1048576).
// ---------------------------------------------------------------------------
__global__ __launch_bounds__(256, 2) void gemm_kernel(
    const half_t* __restrict__ AHI, const half_t* __restrict__ ALO,
    const half_t* __restrict__ WHI,
    const float* __restrict__ BIAS, float* __restrict__ OUT)
{
  __shared__ __align__(16) half_t As[2][128][64];
  __shared__ __align__(16) half_t Bs[2][128][64];
  const int tid = threadIdx.x;
  const int m0 = blockIdx.x * 128, n0 = blockIdx.y * 128;

  f32x16 hh[4], mx[4];
  #pragma unroll
  for (int i = 0; i < 4; ++i) { hh[i] = (f32x16)(0.f); mx[i] = (f32x16)(0.f); }

  const int lane = tid & 63, w = tid >> 6;
  const int rl = lane & 31, kq = lane >> 5;
  const int sw = rl & 7;

  const int r = tid & 127, isB = tid >> 7;
  const int swr = r & 7;
  const half_t* srcHi = isB ? &WHI[(size_t)(n0 + r) * Dd]
                            : &AHI[(size_t)(m0 + r) * Dd];
  const half_t* srcLo = isB ? &WHI[1048576 + (size_t)(n0 + r) * Dd]
                            : &ALO[(size_t)(m0 + r) * Dd];
  half_t* dstRow = isB ? &Bs[0][r][0] : &As[0][r][0];
  const int pc0 = ((0 ^ swr)) * 8, pc1 = ((1 ^ swr)) * 8;
  const int pc2 = ((2 ^ swr)) * 8, pc3 = ((3 ^ swr)) * 8;
  const int pc4 = ((4 ^ swr)) * 8, pc5 = ((5 ^ swr)) * 8;
  const int pc6 = ((6 ^ swr)) * 8, pc7 = ((7 ^ swr)) * 8;

  half8 rg0, rg1, rg2, rg3, rg4, rg5, rg6, rg7;
  LOADREGS(0)
  WRITEREGS(0)
  LOADREGS(32)
  __syncthreads();

  #pragma unroll 1
  for (int k0 = 0; k0 < Dd; k0 += 64) {
    KTILE_MFMA(0)
    WRITEREGS(1)
    if (k0 + 64 < Dd) { LOADREGS(k0 + 64) }
    __syncthreads();
    KTILE_MFMA(1)
    if (k0 + 64 < Dd) { WRITEREGS(0) }
    if (k0 + 96 < Dd) { LOADREGS(k0 + 96) }
    __syncthreads();
  }

  const float bb0 = BIAS[n0 + rl],      bb1 = BIAS[n0 + 32 + rl];
  const float bb2 = BIAS[n0 + 64 + rl], bb3 = BIAS[n0 + 96 + rl];
  #pragma unroll
  for (int j = 0; j < 16; ++j) {
    const int rt = (j & 3) + 8 * (j >> 2) + 4 * kq;
    float* orow = &OUT[(size_t)(m0 + 32 * w + rt) * Dd + n0];
    orow[rl]      = hh[0][j] + mx[0][j] * (1.f / 2048.f) + bb0;
    orow[32 + rl] = hh[1][j] + mx[1][j] * (1.f / 2048.f) + bb1;
    orow[64 + rl] = hh[2][j] + mx[2][j] * (1.f / 2048.f) + bb2;
    orow[96 + rl] = hh[3][j] + mx[3][j] * (1.f / 2048.f) + bb3;
  }
}

// ---------------------------------------------------------------------------
// Kernel 3a: G_c[w][d] = sum_{s in c} K[s][w]*V[s][d]. K from fp16, V fp32.
// ---------------------------------------------------------------------------
__global__ __launch_bounds__(256) void chunk_kv_kernel(
    const half_t* __restrict__ KNH, const float* __restrict__ V,
    float* __restrict__ G)
{
  __shared__ float Ks[64][64];
  __shared__ float Vs[64][64];
  const int tid = threadIdx.x;
  const int c = blockIdx.x, h = blockIdx.y, b = blockIdx.z;
  const int s0 = c * 64;
  const int lr = tid >> 2, lc = (tid & 3) * 16;
  {
    const half_t* krow = &KNH[(size_t)(b * Tt + s0 + lr) * Dd + h * 64 + lc];
    half8 ka = *(const half8*)&krow[0];
    half8 kb = *(const half8*)&krow[8];
    #pragma unroll
    for (int i = 0; i < 8; ++i) {
      Ks[lr][lc + i] = (float)ka[i];
      Ks[lr][lc + 8 + i] = (float)kb[i];
    }
    const float* vrow = &V[(size_t)(b * Tt + s0 + lr) * Dd + h * 64 + lc];
    #pragma unroll
    for (int i = 0; i < 4; ++i)
      *(float4*)&Vs[lr][lc + i * 4] = *(const float4*)&vrow[i * 4];
  }
  __syncthreads();

  const int ty = tid >> 4, tx = tid & 15;
  float g[4][4] = {{0.f}};
  #pragma unroll 4
  for (int s = 0; s < 64; ++s) {
    float4 kv = *(const float4*)&Ks[s][ty * 4];
    float4 vv = *(const float4*)&Vs[s][tx * 4];
    const float* k_ = (const float*)&kv;
    const float* v_ = (const float*)&vv;
    #pragma unroll
    for (int i = 0; i < 4; ++i)
      #pragma unroll
      for (int j = 0; j < 4; ++j)
        g[i][j] = fmaf(k_[i], v_[j], g[i][j]);
  }
  float* Gp = G + (((size_t)(b * Hh + h) * NC + c) << 12);
  #pragma unroll
  for (int i = 0; i < 4; ++i)
    *(float4*)&Gp[(ty * 4 + i) * 64 + tx * 4] =
        make_float4(g[i][0], g[i][1], g[i][2], g[i][3]);
}

// ---------------------------------------------------------------------------
// Kernel 3b: in-place exclusive prefix over NC chunk matrices per (b,h).
// 512 blocks; thread = 1 float, fully coalesced.
// ---------------------------------------------------------------------------
__global__ __launch_bounds__(256) void prefix_kernel(float* __restrict__ G)
{
  const int seg = blockIdx.x, h = blockIdx.y, b = blockIdx.z;
  float* base = G + (((size_t)(b * Hh + h) * NC) << 12) + seg * 256 + threadIdx.x;
  float acc = 0.f;
  #pragma unroll 4
  for (int c = 0; c < NC; ++c) {
    float* p = base + ((size_t)c << 12);
    const float g = *p;
    *p = acc;
    acc += g;
  }
}

// ---------------------------------------------------------------------------
// Kernel 3c: O_c = (Q_c M_c + tril(Q_c K_c^T) V_c) * scale/sqrt(t+1).
// Q,K from fp16; out split to fp16 hi/lo (lo x2048), aliasing qnh/knh.
// ---------------------------------------------------------------------------
__global__ __launch_bounds__(256) void attn_chunk_kernel(
    const half_t* __restrict__ QNH, const half_t* __restrict__ KNH,
    const float* __restrict__ V, const float* __restrict__ M,
    const float* __restrict__ SCALE,
    half_t* __restrict__ ATTHI, half_t* __restrict__ ATTLO)
{
  __shared__ float Qt[64][68];
  __shared__ float Kt[64][68];
  __shared__ float SM[64][68];
  __shared__ float Vs[64][64];
  const int tid = threadIdx.x;
  const int c = blockIdx.x, h = blockIdx.y, b = blockIdx.z;
  const int t0 = c * 64;
  const int lr = tid >> 2, lc = (tid & 3) * 16;
  {
    const half_t* qrow = &QNH[(size_t)(b * Tt + t0 + lr) * Dd + h * 64 + lc];
    const half_t* krow = &KNH[(size_t)(b * Tt + t0 + lr) * Dd + h * 64 + lc];
    half8 qa = *(const half8*)&qrow[0];
    half8 qb = *(const half8*)&qrow[8];
    half8 ka = *(const half8*)&krow[0];
    half8 kb = *(const half8*)&krow[8];
    #pragma unroll
    for (int i = 0; i < 8; ++i) {
      Qt[lc + i][lr] = (float)qa[i];     Qt[lc + 8 + i][lr] = (float)qb[i];
      Kt[lc + i][lr] = (float)ka[i];     Kt[lc + 8 + i][lr] = (float)kb[i];
    }
    const float* vrow = &V[(size_t)(b * Tt + t0 + lr) * Dd + h * 64 + lc];
    const float* mrow = &M[(((size_t)(b * Hh + h) * NC + c) << 12) + lr * 64 + lc];
    #pragma unroll
    for (int i = 0; i < 4; ++i) {
      *(float4*)&Vs[lr][lc + i * 4] = *(const float4*)&vrow[i * 4];
      *(float4*)&SM[lr][lc + i * 4] = *(const float4*)&mrow[i * 4];
    }
  }
  __syncthreads();

  const int ty = tid >> 4, tx = tid & 15;
  float o[4][4] = {{0.f}};
  float sc[4][4] = {{0.f}};

  #pragma unroll 4
  for (int w = 0; w < 64; ++w) {
    float4 qv = *(const float4*)&Qt[w][ty * 4];
    float4 mv = *(const float4*)&SM[w][tx * 4];
    float4 kv = *(const float4*)&Kt[w][tx * 4];
    const float* q_ = (const float*)&qv;
    const float* m_ = (const float*)&mv;
    const float* k_ = (const float*)&kv;
    #pragma unroll
    for (int i = 0; i < 4; ++i) {
      float qq = q_[i];
      #pragma unroll
      for (int j = 0; j < 4; ++j) {
        o[i][j]  = fmaf(qq, m_[j], o[i][j]);
        sc[i][j] = fmaf(qq, k_[j], sc[i][j]);
      }
    }
  }
  __syncthreads();

  #pragma unroll
  for (int i = 0; i < 4; ++i) {
    const int lt = ty * 4 + i;
    #pragma unroll
    for (int j = 0; j < 4; ++j) {
      const int ls = tx * 4 + j;
      SM[ls][lt] = (ls <= lt) ? sc[i][j] : 0.f;
    }
  }
  __syncthreads();

  #pragma unroll 4
  for (int s = 0; s < 64; ++s) {
    float4 sv = *(const float4*)&SM[s][ty * 4];
    float4 vv = *(const float4*)&Vs[s][tx * 4];
    const float* s_ = (const float*)&sv;
    const float* v_ = (const float*)&vv;
    #pragma unroll
    for (int i = 0; i < 4; ++i)
      #pragma unroll
      for (int j = 0; j < 4; ++j)
        o[i][j] = fmaf(s_[i], v_[j], o[i][j]);
  }

  const float sch = SCALE[h];
  #pragma unroll
  for (int i = 0; i < 4; ++i) {
    const int t = t0 + ty * 4 + i;
    const float fac = sch / sqrtf((float)(t + 1));
    half4h hv, lv;
    #pragma unroll
    for (int j = 0; j < 4; ++j) {
      float v = o[i][j] * fac;
      half_t hx = (half_t)v;
      hv[j] = hx; lv[j] = (half_t)((v - (float)hx) * 2048.f);
    }
    *(half4h*)&ATTHI[(size_t)(b * Tt + t) * Dd + h * 64 + tx * 4] = hv;
    *(half4h*)&ATTLO[(size_t)(b * Tt + t) * Dd + h * 64 + tx * 4] = lv;
  }
}

// ---------------------------------------------------------------------------
extern "C" void kernel_launch(void* const* d_in, const int* in_sizes, int n_in,
                              void* d_out, int out_size, void* d_ws, size_t ws_size,
                              hipStream_t stream) {
  const float* x   = (const float*)d_in[0];
  const float* Wqf = (const float*)d_in[1];
  const float* bqf = (const float*)d_in[2];
  const float* Wkf = (const float*)d_in[3];
  const float* bkf = (const float*)d_in[4];
  const float* Wqp = (const float*)d_in[5];
  const float* bqp = (const float*)d_in[6];
  const float* Wkp = (const float*)d_in[7];
  const float* bkp = (const float*)d_in[8];
  const float* Wv  = (const float*)d_in[9];
  const float* bv  = (const float*)d_in[10];
  const float* Wo  = (const float*)d_in[11];
  const float* bo  = (const float*)d_in[12];
  const float* scale = (const float*)d_in[13];

  // ws layout (56 MB): Wsplit 24 MB | qnh 8 MB | knh 8 MB | G 16 MB
  half_t* WSP = (half_t*)d_ws;                 // 6 mats x (hi 1M + lo 1M) halves
  half_t* qnh = WSP + 12582912;                // 4,194,304 halves
  half_t* knh = qnh + 4194304;
  float*  G   = (float*)(knh + 4194304);
  half_t* xhi = (half_t*)G;                    // x halves alias G: dead before
  half_t* xlo = xhi + 4194304;                 // chunk_kv writes G
  float*  vbuf = (float*)d_out;                // v lives in d_out, consumed
                                               // before the final out-gemm

  xsplit_kernel<<<dim3(2048), 256, 0, stream>>>(x, xhi, xlo);

  // mat order in WSP: 0=qf 1=qp 2=kf 3=kp 4=v 5=o
  wsplit_kernel<<<dim3(16, 16, 6), 256, 0, stream>>>(Wqf, Wqp, Wkf, Wkp, Wv, Wo, WSP);

  proj_kernel<<<dim3(Tt / 128, Hh, Bb * 2), 256, 0, stream>>>(
      xhi, xlo, WSP, bqf, bqp, bkf, bkp, qnh, knh);

  gemm_kernel<<<dim3((Bb * Tt) / 128, Dd / 128), 256, 0, stream>>>(
      xhi, xlo, WSP + (size_t)4 * 2097152, bv, vbuf);

  chunk_kv_kernel<<<dim3(NC, Hh, Bb), 256, 0, stream>>>(knh, vbuf, G);
  prefix_kernel<<<dim3(16, Hh, Bb), 256, 0, stream>>>(G);
  attn_chunk_kernel<<<dim3(NC, Hh, Bb), 256, 0, stream>>>(
      qnh, knh, vbuf, G, scale, qnh /*atthi*/, knh /*attlo*/);

  gemm_kernel<<<dim3((Bb * Tt) / 128, Dd / 128), 256, 0, stream>>>(
      qnh, knh, WSP + (size_t)5 * 2097152, bo, (float*)d_out);
}